// Round 1
// baseline (437.237 us; speedup 1.0000x reference)
//
#include <hip/hip_runtime.h>

#define T_IN   512
#define T_OUT  128
#define BATCH  65536

// sigmoid(x) = 1/(1+exp(-x)), exp(-x) = exp2(-x*log2(e))
__device__ __forceinline__ float sigm(float v) {
    float e = __builtin_amdgcn_exp2f(-1.44269504088896340736f * v);
    return __builtin_amdgcn_rcpf(1.0f + e);
}
// tanh(x) = 1 - 2/(1+exp(2x)), exp(2x) = exp2(2*log2(e)*x)
__device__ __forceinline__ float tanh_fast(float v) {
    float e = __builtin_amdgcn_exp2f(2.88539008177792681472f * v);
    return 1.0f - 2.0f * __builtin_amdgcn_rcpf(1.0f + e);
}

// 8 lanes per batch element. Lane k owns hidden unit k and gate rows
// {k, k+8, k+16} (r,z,n) of the [24,8] W_hh. Weights live in VGPRs.
// Per-step h allgather via 3 LDS ops within the wave (no barrier needed:
// each 8-lane group is inside one wave64; HW lgkmcnt orders write->read).
__global__ __launch_bounds__(256) void gru_seq2seq(
    const float* __restrict__ x,
    const float* __restrict__ eWih, const float* __restrict__ eWhh,
    const float* __restrict__ eBih, const float* __restrict__ eBhh,
    const float* __restrict__ dWih, const float* __restrict__ dWhh,
    const float* __restrict__ dBih, const float* __restrict__ dBhh,
    const float* __restrict__ fcW,  const float* __restrict__ fcB,
    float* __restrict__ out)
{
    __shared__ __align__(16) float hsh[32][8];   // 32 elems/block
    const int tid = threadIdx.x;
    const int k   = tid & 7;        // hidden unit owned by this lane
    const int el  = tid >> 3;       // local batch element 0..31
    const int e   = (int)blockIdx.x * 32 + el;   // global batch element

    // ---------------- encoder weights (rows k, k+8, k+16) ----------------
    float wr[8], wz[8], wn[8];
    {
        const float4* W4 = (const float4*)eWhh;   // [24][8] row-major, rows 16B-aligned
        float4 r0 = W4[2*k+0],      r1 = W4[2*k+1];
        float4 z0 = W4[2*(k+8)+0],  z1 = W4[2*(k+8)+1];
        float4 n0 = W4[2*(k+16)+0], n1 = W4[2*(k+16)+1];
        wr[0]=r0.x; wr[1]=r0.y; wr[2]=r0.z; wr[3]=r0.w;
        wr[4]=r1.x; wr[5]=r1.y; wr[6]=r1.z; wr[7]=r1.w;
        wz[0]=z0.x; wz[1]=z0.y; wz[2]=z0.z; wz[3]=z0.w;
        wz[4]=z1.x; wz[5]=z1.y; wz[6]=z1.z; wz[7]=z1.w;
        wn[0]=n0.x; wn[1]=n0.y; wn[2]=n0.z; wn[3]=n0.w;
        wn[4]=n1.x; wn[5]=n1.y; wn[6]=n1.z; wn[7]=n1.w;
    }
    float wir = eWih[k], wiz = eWih[k+8], win = eWih[k+16];   // W_ih is [24][1]
    float bir = eBih[k], biz = eBih[k+8], bin_ = eBih[k+16];
    float bhr = eBhh[k], bhz = eBhh[k+8], bhn = eBhh[k+16];

    float h = 0.0f;                       // own h_k
    float hv[8];                          // full h vector (replicated)
    #pragma unroll
    for (int j = 0; j < 8; ++j) hv[j] = 0.0f;

    // ---------------- encoder: 512 steps ----------------
    float xt  = x[e];                     // x[t][e], layout [T,B,1]
    float xt1 = x[BATCH + e];
    #pragma unroll 1
    for (int t = 0; t < T_IN; ++t) {
        const int pf = (t + 2 < T_IN) ? (t + 2) : (T_IN - 1);
        const float xt2 = x[pf * BATCH + e];      // prefetch 2 ahead

        float ar = bhr, az = bhz, an = bhn;       // gh rows incl. b_hh
        #pragma unroll
        for (int j = 0; j < 8; ++j) {
            ar = fmaf(wr[j], hv[j], ar);
            az = fmaf(wz[j], hv[j], az);
            an = fmaf(wn[j], hv[j], an);
        }
        const float r = sigm(fmaf(xt, wir, bir) + ar);
        const float z = sigm(fmaf(xt, wiz, biz) + az);
        const float n = tanh_fast(fmaf(xt, win, bin_) + r * an);
        h = fmaf(z, h - n, n);                    // (1-z)*n + z*h

        // intra-wave allgather of new h
        hsh[el][k] = h;
        asm volatile("" ::: "memory");
        const float4 ha = *(const float4*)&hsh[el][0];
        const float4 hb = *(const float4*)&hsh[el][4];
        asm volatile("" ::: "memory");
        hv[0]=ha.x; hv[1]=ha.y; hv[2]=ha.z; hv[3]=ha.w;
        hv[4]=hb.x; hv[5]=hb.y; hv[6]=hb.z; hv[7]=hb.w;

        xt = xt1; xt1 = xt2;
    }

    // ---------------- decoder weights (reuse registers) ----------------
    {
        const float4* W4 = (const float4*)dWhh;
        float4 r0 = W4[2*k+0],      r1 = W4[2*k+1];
        float4 z0 = W4[2*(k+8)+0],  z1 = W4[2*(k+8)+1];
        float4 n0 = W4[2*(k+16)+0], n1 = W4[2*(k+16)+1];
        wr[0]=r0.x; wr[1]=r0.y; wr[2]=r0.z; wr[3]=r0.w;
        wr[4]=r1.x; wr[5]=r1.y; wr[6]=r1.z; wr[7]=r1.w;
        wz[0]=z0.x; wz[1]=z0.y; wz[2]=z0.z; wz[3]=z0.w;
        wz[4]=z1.x; wz[5]=z1.y; wz[6]=z1.z; wz[7]=z1.w;
        wn[0]=n0.x; wn[1]=n0.y; wn[2]=n0.z; wn[3]=n0.w;
        wn[4]=n1.x; wn[5]=n1.y; wn[6]=n1.z; wn[7]=n1.w;
    }
    wir = dWih[k]; wiz = dWih[k+8]; win = dWih[k+16];
    bir = dBih[k]; biz = dBih[k+8]; bin_ = dBih[k+16];
    bhr = dBhh[k]; bhz = dBhh[k+8]; bhn = dBhh[k+16];
    float fw[8];
    {
        const float4 f0 = *(const float4*)&fcW[0];
        const float4 f1 = *(const float4*)&fcW[4];
        fw[0]=f0.x; fw[1]=f0.y; fw[2]=f0.z; fw[3]=f0.w;
        fw[4]=f1.x; fw[5]=f1.y; fw[6]=f1.z; fw[7]=f1.w;
    }
    const float fb = fcB[0];

    // ---------------- decoder: 128 steps, feed back own prediction ----------------
    float inp = x[(T_IN - 1) * BATCH + e];        // x[-1]
    float* outp = out + e;
    #pragma unroll 1
    for (int t = 0; t < T_OUT; ++t) {
        float ar = bhr, az = bhz, an = bhn;
        #pragma unroll
        for (int j = 0; j < 8; ++j) {
            ar = fmaf(wr[j], hv[j], ar);
            az = fmaf(wz[j], hv[j], az);
            an = fmaf(wn[j], hv[j], an);
        }
        const float r = sigm(fmaf(inp, wir, bir) + ar);
        const float z = sigm(fmaf(inp, wiz, biz) + az);
        const float n = tanh_fast(fmaf(inp, win, bin_) + r * an);
        h = fmaf(z, h - n, n);

        hsh[el][k] = h;
        asm volatile("" ::: "memory");
        const float4 ha = *(const float4*)&hsh[el][0];
        const float4 hb = *(const float4*)&hsh[el][4];
        asm volatile("" ::: "memory");
        hv[0]=ha.x; hv[1]=ha.y; hv[2]=ha.z; hv[3]=ha.w;
        hv[4]=hb.x; hv[5]=hb.y; hv[6]=hb.z; hv[7]=hb.w;

        // y = h' @ fc_W.T + fc_b  (every lane computes it; needed for feedback)
        float y = fb;
        #pragma unroll
        for (int j = 0; j < 8; ++j) y = fmaf(fw[j], hv[j], y);

        if (k == 0) outp[t * BATCH] = y;          // out[t][e][0]
        inp = y;
    }
}

extern "C" void kernel_launch(void* const* d_in, const int* in_sizes, int n_in,
                              void* d_out, int out_size, void* d_ws, size_t ws_size,
                              hipStream_t stream) {
    const float* x    = (const float*)d_in[0];
    const float* eWih = (const float*)d_in[1];
    const float* eWhh = (const float*)d_in[2];
    const float* eBih = (const float*)d_in[3];
    const float* eBhh = (const float*)d_in[4];
    const float* dWih = (const float*)d_in[5];
    const float* dWhh = (const float*)d_in[6];
    const float* dBih = (const float*)d_in[7];
    const float* dBhh = (const float*)d_in[8];
    const float* fcW  = (const float*)d_in[9];
    const float* fcB  = (const float*)d_in[10];
    float* out = (float*)d_out;

    dim3 grid(BATCH / 32);   // 2048 blocks, 32 batch elems per block
    dim3 block(256);         // 8 lanes per batch elem
    gru_seq2seq<<<grid, block, 0, stream>>>(x, eWih, eWhh, eBih, eBhh,
                                            dWih, dWhh, dBih, dBhh,
                                            fcW, fcB, out);
}

// Round 2
// 418.139 us; speedup vs baseline: 1.0457x; 1.0457x over previous
//
#include <hip/hip_runtime.h>

#define T_IN   512
#define T_OUT  128
#define BATCH  65536

typedef float v2f __attribute__((ext_vector_type(2)));
typedef float v4f __attribute__((ext_vector_type(4)));

__device__ __forceinline__ float exp2_fast(float v) { return __builtin_amdgcn_exp2f(v); }
__device__ __forceinline__ float rcp_fast(float v)  { return __builtin_amdgcn_rcpf(v); }

// 8 lanes per batch element; lane k owns hidden unit k and gate rows {k,k+8,k+16}.
// All weights in VGPRs, pre-scaled by the exp2 constants:
//   r,z: sigmoid(s) = rcp(1 + exp2(-log2e * s))  -> fold CR=-log2e into W,b
//   n:   tanh(s)    = 1 - 2*rcp(1 + exp2(2log2e * s)) -> fold CN=2log2e
// Matmul done as 12 v_pk_fma_f32 over j-pairs (h arrives as reg-quads from LDS).
__global__ __launch_bounds__(256) void gru_seq2seq(
    const float* __restrict__ x,
    const float* __restrict__ eWih, const float* __restrict__ eWhh,
    const float* __restrict__ eBih, const float* __restrict__ eBhh,
    const float* __restrict__ dWih, const float* __restrict__ dWhh,
    const float* __restrict__ dBih, const float* __restrict__ dBhh,
    const float* __restrict__ fcW,  const float* __restrict__ fcB,
    float* __restrict__ out)
{
    __shared__ __align__(16) float hsh[32][8];
    const int tid = threadIdx.x;
    const int k   = tid & 7;
    const int el  = tid >> 3;
    const int e   = (int)blockIdx.x * 32 + el;

    const float CR = -1.44269504088896340736f;   // -log2(e)
    const float CN =  2.88539008177792681472f;   //  2*log2(e)

    v2f wr[4], wz[4], wn[4];
    float wir, wiz, win, bbr, bbz, binS, bhnS;

    auto load_w = [&](const float* Wih, const float* Whh,
                      const float* Bih, const float* Bhh) {
        #pragma unroll
        for (int p = 0; p < 4; ++p) {
            wr[p] = v2f{ Whh[k*8      + 2*p] * CR, Whh[k*8      + 2*p + 1] * CR };
            wz[p] = v2f{ Whh[(k+8)*8  + 2*p] * CR, Whh[(k+8)*8  + 2*p + 1] * CR };
            wn[p] = v2f{ Whh[(k+16)*8 + 2*p] * CN, Whh[(k+16)*8 + 2*p + 1] * CN };
        }
        wir = Wih[k]    * CR;  wiz = Wih[k+8] * CR;  win = Wih[k+16] * CN;
        bbr = (Bih[k]   + Bhh[k])   * CR;            // merged bias, scaled
        bbz = (Bih[k+8] + Bhh[k+8]) * CR;
        binS = Bih[k+16] * CN;                       // i_n bias (outside r*)
        bhnS = Bhh[k+16] * CN;                       // h_n bias (inside r*)
    };

    load_w(eWih, eWhh, eBih, eBhh);

    float h = 0.0f;
    v4f hva = {0.f, 0.f, 0.f, 0.f};   // h[0..3] replicated
    v4f hvb = {0.f, 0.f, 0.f, 0.f};   // h[4..7]

    auto cell = [&](float xin) {
        v2f h01 = __builtin_shufflevector(hva, hva, 0, 1);
        v2f h23 = __builtin_shufflevector(hva, hva, 2, 3);
        v2f h45 = __builtin_shufflevector(hvb, hvb, 0, 1);
        v2f h67 = __builtin_shufflevector(hvb, hvb, 2, 3);

        v2f ar = v2f{ bbr,  0.f };
        v2f az = v2f{ bbz,  0.f };
        v2f an = v2f{ bhnS, 0.f };
        ar = __builtin_elementwise_fma(wr[0], h01, ar);
        az = __builtin_elementwise_fma(wz[0], h01, az);
        an = __builtin_elementwise_fma(wn[0], h01, an);
        ar = __builtin_elementwise_fma(wr[1], h23, ar);
        az = __builtin_elementwise_fma(wz[1], h23, az);
        an = __builtin_elementwise_fma(wn[1], h23, an);
        ar = __builtin_elementwise_fma(wr[2], h45, ar);
        az = __builtin_elementwise_fma(wz[2], h45, az);
        an = __builtin_elementwise_fma(wn[2], h45, an);
        ar = __builtin_elementwise_fma(wr[3], h67, ar);
        az = __builtin_elementwise_fma(wz[3], h67, az);
        an = __builtin_elementwise_fma(wn[3], h67, an);

        const float sr = fmaf(xin, wir, ar.x + ar.y);   // scaled pre-act r
        const float sz = fmaf(xin, wiz, az.x + az.y);   // scaled pre-act z
        const float hn = an.x + an.y;                   // scaled h_n part

        const float er = exp2_fast(sr);
        const float ez = exp2_fast(sz);
        const float dr = 1.0f + er;
        const float dz = 1.0f + ez;
        const float rp = rcp_fast(dr * dz);             // shared reciprocal
        const float r  = dz * rp;                       // = 1/(1+er)
        const float z  = dr * rp;                       // = 1/(1+ez)

        float pre = fmaf(xin, win, binS);
        pre = fmaf(r, hn, pre);
        const float en = exp2_fast(pre);
        const float rn = rcp_fast(1.0f + en);
        const float n  = fmaf(-2.0f, rn, 1.0f);         // tanh

        h = fmaf(z, h - n, n);                          // (1-z)*n + z*h

        hsh[el][k] = h;
        asm volatile("" ::: "memory");
        hva = *(const v4f*)&hsh[el][0];
        hvb = *(const v4f*)&hsh[el][4];
        asm volatile("" ::: "memory");
    };

    // ---------------- encoder: 512 steps, prefetch distance 2, tail peeled ----------------
    const float* xp = x + e;
    float x0 = xp[0];
    float x1 = xp[BATCH];
    xp += 2 * (size_t)BATCH;
    #pragma unroll 1
    for (int t = 0; t < T_IN - 2; ++t) {
        const float x2 = *xp; xp += BATCH;
        cell(x0);
        x0 = x1; x1 = x2;
    }
    cell(x0);      // t = 510
    cell(x1);      // t = 511; x1 == x[511] == decoder's first input

    // ---------------- decoder: 128 steps ----------------
    load_w(dWih, dWhh, dBih, dBhh);
    v2f fw2[4];
    #pragma unroll
    for (int p = 0; p < 4; ++p) fw2[p] = v2f{ fcW[2*p], fcW[2*p+1] };
    const float fb = fcB[0];

    float inp = x1;
    float* outp = out + e;
    #pragma unroll 1
    for (int t = 0; t < T_OUT; ++t) {
        cell(inp);
        v2f h01 = __builtin_shufflevector(hva, hva, 0, 1);
        v2f h23 = __builtin_shufflevector(hva, hva, 2, 3);
        v2f h45 = __builtin_shufflevector(hvb, hvb, 0, 1);
        v2f h67 = __builtin_shufflevector(hvb, hvb, 2, 3);
        v2f ay = v2f{ fb, 0.f };
        ay = __builtin_elementwise_fma(fw2[0], h01, ay);
        ay = __builtin_elementwise_fma(fw2[1], h23, ay);
        ay = __builtin_elementwise_fma(fw2[2], h45, ay);
        ay = __builtin_elementwise_fma(fw2[3], h67, ay);
        const float y = ay.x + ay.y;
        if (k == 0) outp[t * BATCH] = y;
        inp = y;
    }
}

extern "C" void kernel_launch(void* const* d_in, const int* in_sizes, int n_in,
                              void* d_out, int out_size, void* d_ws, size_t ws_size,
                              hipStream_t stream) {
    const float* x    = (const float*)d_in[0];
    const float* eWih = (const float*)d_in[1];
    const float* eWhh = (const float*)d_in[2];
    const float* eBih = (const float*)d_in[3];
    const float* eBhh = (const float*)d_in[4];
    const float* dWih = (const float*)d_in[5];
    const float* dWhh = (const float*)d_in[6];
    const float* dBih = (const float*)d_in[7];
    const float* dBhh = (const float*)d_in[8];
    const float* fcW  = (const float*)d_in[9];
    const float* fcB  = (const float*)d_in[10];
    float* out = (float*)d_out;

    dim3 grid(BATCH / 32);   // 2048 blocks, 32 batch elems per block
    dim3 block(256);         // 8 lanes per batch elem
    gru_seq2seq<<<grid, block, 0, stream>>>(x, eWih, eWhh, eBih, eBhh,
                                            dWih, dWhh, dBih, dBhh,
                                            fcW, fcB, out);
}